// Round 12
// baseline (506.809 us; speedup 1.0000x reference)
//
#include <hip/hip_runtime.h>

// ---------------------------------------------------------------------------
// CWRRTEWindowCell on MI355X (gfx950). FP32 I/O, bf16 MFMA internals.
// B=32, W=T=512, D=512, H=8, DH=64, K=64.
// R19: RMSNorm#2 fused algebraically: rms(h1)@W1 = inv[row]*(h1@W1), inv
// applied to MLP1 accumulators BEFORE silu. Wo-gemm epilogue writes h1b
// (bf16 h1) + per-row ssq (shfl-reduced, 1 atomic/row/wave-pair); rms_k
// dispatch deleted (32MB read + 16MB write + launch). 10 -> 9 dispatches.
// bf16 rounding error is scale-invariant -> same absmax path.
// R18: mlp1 = R8 body (82us, 32KB LDS, 5 blocks/CU). R17 lesson: in the
// 2-barrier loop, arithmetic-intensity gains never pay for occupancy
// losses (TLP carries the stage drain). R16: epi2/gemv split (G1).
// R13/R14: rope-as-table in attn; prep mega-kernel. R12: fused QKV gemm.
// R11: default dispatch optimal for [many-bm x few-bn]. R9/R10: schedule
// surgery on the 2-barrier loop regresses. R8: T2 XOR-swizzle (core win).
// ---------------------------------------------------------------------------

#define DEVI __device__ __forceinline__
typedef unsigned short u16;
typedef unsigned int   u32;
typedef __bf16 v8bf __attribute__((ext_vector_type(8)));
typedef float  v4f  __attribute__((ext_vector_type(4)));

DEVI float bf2f(u16 u) { u32 v = ((u32)u) << 16; return __builtin_bit_cast(float, v); }
DEVI u16 f2bf(float f) {
  u32 x = __builtin_bit_cast(u32, f);
  u32 r = x + 0x7fffu + ((x >> 16) & 1u);
  return (u16)(r >> 16);
}
DEVI uint4 pack8(const float* f) {
  u32 a[4];
#pragma unroll
  for (int i = 0; i < 4; ++i)
    a[i] = (u32)f2bf(f[2*i]) | ((u32)f2bf(f[2*i+1]) << 16);
  uint4 v; v.x = a[0]; v.y = a[1]; v.z = a[2]; v.w = a[3]; return v;
}
DEVI void ld8f(const float* p, float* f) {
  float4 a = *(const float4*)p, b = *(const float4*)(p + 4);
  f[0]=a.x; f[1]=a.y; f[2]=a.z; f[3]=a.w; f[4]=b.x; f[5]=b.y; f[6]=b.z; f[7]=b.w;
}
DEVI void st8f(float* p, const float* f) {
  *(float4*)p       = make_float4(f[0], f[1], f[2], f[3]);
  *(float4*)(p + 4) = make_float4(f[4], f[5], f[6], f[7]);
}
DEVI v8bf ldfrag(const u16* p) { return __builtin_bit_cast(v8bf, *(const uint4*)p); }

// rotate one (even,odd) bf16 pair packed in a u32 by (c,s)
DEVI u32 rot1(u32 w, float c, float s) {
  float e = bf2f((u16)(w & 0xffffu)), o = bf2f((u16)(w >> 16));
  float ne = e * c - o * s;
  float no = e * s + o * c;
  return (u32)f2bf(ne) | ((u32)f2bf(no) << 16);
}

// async global->LDS, 16B per lane; lds dest wave-uniform base + lane*16.
DEVI void async16(const u16* g, u16* l) {
  __builtin_amdgcn_global_load_lds(
      (const __attribute__((address_space(1))) void*)g,
      (__attribute__((address_space(3))) void*)l, 16, 0, 0);
}

DEVI float wave_sum64(float v) {
  v += __shfl_xor(v, 1);  v += __shfl_xor(v, 2);  v += __shfl_xor(v, 4);
  v += __shfl_xor(v, 8);  v += __shfl_xor(v, 16); v += __shfl_xor(v, 32);
  return v;
}

__device__ float block_sum256(float v, float* sred) {
  v = wave_sum64(v);
  int w = threadIdx.x >> 6;
  __syncthreads();
  if ((threadIdx.x & 63) == 0) sred[w] = v;
  __syncthreads();
  return sred[0] + sred[1] + sred[2] + sred[3];
}

// ---------------------------------------------------------------------------
// PREP mega-kernel. Block-range decode:
//   [0,256)     Wq -> WTqkv rows 0-511     (scale rms1)
//   [256,512)   Wk -> WTqkv rows 512-1023  (scale rms_kv)
//   [512,768)   Wv -> WTqkv rows 1024-1535 (scale rms_kv)
//   [768,1024)  Wo -> WTo
//   [1024,3072) W1 -> WT1 (scale rms2)
//   [3072,4096) W2 -> WT2
//   [4096,4102) bias_qkv = [bq|bk|bv]
//   [4102,4166) rope table tbl[t][f] = {cos,sin}(pos[t]*10000^(-2f/64))
//   [4166,4230) qw_g = 0 (atomic accumulator, re-zeroed each replay)
//   [4230,4294) rssq = 0 (atomic accumulator, re-zeroed each replay)
//   [4294,8390) RMSNorm x -> nrm (bf16)
// ---------------------------------------------------------------------------
__global__ __launch_bounds__(256) void prep_k(
    const float* __restrict__ Wq, const float* __restrict__ Wk,
    const float* __restrict__ Wv, const float* __restrict__ Wo,
    const float* __restrict__ W1, const float* __restrict__ W2,
    const float* __restrict__ rms1, const float* __restrict__ rms_kv,
    const float* __restrict__ rms2, u16* __restrict__ WTqkv,
    u16* __restrict__ WTo, u16* __restrict__ WT1, u16* __restrict__ WT2,
    const float* __restrict__ bq, const float* __restrict__ bk,
    const float* __restrict__ bv, float* __restrict__ bias_qkv,
    const int* __restrict__ pos, float* __restrict__ tbl,
    float* __restrict__ qw_g, float* __restrict__ rssq,
    const float* __restrict__ x, u16* __restrict__ nrm) {
  int id = blockIdx.x;
  int tid = threadIdx.x;
  if (id >= 4294) {  // RMSNorm
    int w = tid >> 6, lane = tid & 63;
    size_t row = (size_t)(id - 4294) * 4 + w;
    float xf[8]; ld8f(x + row * 512 + lane * 8, xf);
    float ss = 0.f;
#pragma unroll
    for (int i = 0; i < 8; ++i) ss += xf[i] * xf[i];
    ss = wave_sum64(ss);
    float inv = rsqrtf(ss * (1.f / 512.f) + 1e-6f);
    float of[8];
#pragma unroll
    for (int i = 0; i < 8; ++i) of[i] = xf[i] * inv;
    *(uint4*)(nrm + row * 512 + lane * 8) = pack8(of);
    return;
  }
  if (id >= 4230) {  // zero rssq
    rssq[(id - 4230) * 256 + tid] = 0.f;
    return;
  }
  if (id >= 4166) {  // zero qw_g
    qw_g[(id - 4166) * 256 + tid] = 0.f;
    return;
  }
  if (id >= 4102) {  // rope table
    int idx = (id - 4102) * 256 + tid;   // 0..16383
    int t = idx >> 5, f = idx & 31;
    float freq = exp2f(-0.41524101186f * (float)f);  // 10000^(-2f/64)
    float ang = (float)pos[t] * freq;
    float sv, cv;
    sincosf(ang, &sv, &cv);
    tbl[t * 64 + f * 2]     = cv;
    tbl[t * 64 + f * 2 + 1] = sv;
    return;
  }
  if (id >= 4096) {  // bias concat
    int j = (id - 4096) * 256 + tid;
    bias_qkv[j] = j < 512 ? bq[j] : (j < 1024 ? bk[j - 512] : bv[j - 1024]);
    return;
  }
  const float* in; const float* scale; u16* outp; int R, C, bx, by;
  if (id < 256)       { in=Wq; scale=rms1;   outp=WTqkv;            R=512;  C=512;  int l=id;       bx=l&15;  by=l>>4; }
  else if (id < 512)  { in=Wk; scale=rms_kv; outp=WTqkv+512*512;    R=512;  C=512;  int l=id-256;   bx=l&15;  by=l>>4; }
  else if (id < 768)  { in=Wv; scale=rms_kv; outp=WTqkv+1024*512;   R=512;  C=512;  int l=id-512;   bx=l&15;  by=l>>4; }
  else if (id < 1024) { in=Wo; scale=nullptr;outp=WTo;              R=512;  C=512;  int l=id-768;   bx=l&15;  by=l>>4; }
  else if (id < 3072) { in=W1; scale=rms2;   outp=WT1;              R=512;  C=4096; int l=id-1024;  bx=l&127; by=l>>7; }
  else                { in=W2; scale=nullptr;outp=WT2;              R=2048; C=512;  int l=id-3072;  bx=l&15;  by=l>>4; }
  __shared__ u16 t[32][33];
  int c0 = bx * 32, r0 = by * 32;
  int lc = tid & 31, lr = tid >> 5;
  for (int rr = lr; rr < 32; rr += 8) {
    float v = in[(size_t)(r0 + rr) * C + c0 + lc];
    if (scale) v *= scale[r0 + rr];
    t[rr][lc] = f2bf(v);
  }
  __syncthreads();
  for (int rr = lr; rr < 32; rr += 8)
    outp[(size_t)(c0 + rr) * R + r0 + lc] = t[lc][rr];
}

// ---------------------------------------------------------------------------
// 128x128-tile GEMM (R8 body): A[M,Kd](bf16) @ BT[N][Kd](bf16).
// R8 swizzle: source column pre-swizzled (slot ^= row&7), read column XORs
// (m&7)*8. bias indexed by gcol (stacked bias for fused QKV).
// Optional colsum epilogue -> atomicAdd colsum[b*512+col]/512 (b=bm>>2).
// R19: optional outb2 (second bf16 copy of v) + rowssq (per-row sum of v^2,
// shfl-reduced over the 16 m-lanes, atomicAdd from m==0).
// ---------------------------------------------------------------------------
__global__ __launch_bounds__(256) void gemm128_k(const u16* __restrict__ A,
                                                 const u16* __restrict__ BT,
                                                 const float* __restrict__ bias,
                                                 const float* __restrict__ resf,
                                                 u16* __restrict__ outb,
                                                 float* __restrict__ outf,
                                                 u16* __restrict__ outb2,
                                                 float* __restrict__ rowssq,
                                                 float* __restrict__ colsum,
                                                 int N, int Kd) {
  __shared__ u16 As[128 * 64];
  __shared__ u16 Bs[128 * 64];
  int tid = threadIdx.x;
  int w = tid >> 6, lane = tid & 63;
  int m = lane & 15, quad = lane >> 4;
  int wm = w >> 1, wn = w & 1;
  int bm = blockIdx.x, bn = blockIdx.y;
  v4f acc[4][4] = {};
  const int gswz = ((lane & 7) ^ (lane >> 3)) * 8;  // source-side swizzle
  const u16* Ag = A + (size_t)(bm * 128 + w * 32 + (lane >> 3)) * Kd + gswz;
  const u16* Bg = BT + (size_t)(bn * 128 + w * 32 + (lane >> 3)) * Kd + gswz;
  u16* Al = &As[w * 32 * 64];
  u16* Bl = &Bs[w * 32 * 64];
  const int rsw = (m & 7) * 8;                      // read-side swizzle
  for (int k0 = 0; k0 < Kd; k0 += 64) {
#pragma unroll
    for (int it = 0; it < 4; ++it) {
      async16(Ag + (size_t)it * 8 * Kd + k0, Al + it * 8 * 64);
      async16(Bg + (size_t)it * 8 * Kd + k0, Bl + it * 8 * 64);
    }
    __syncthreads();
#pragma unroll
    for (int kk = 0; kk < 2; ++kk) {
      v8bf af[4], bfr[4];
#pragma unroll
      for (int i = 0; i < 4; ++i)
        af[i] = ldfrag(&As[(wm * 64 + i * 16 + m) * 64 +
                           ((kk * 32 + quad * 8) ^ rsw)]);
#pragma unroll
      for (int j = 0; j < 4; ++j)
        bfr[j] = ldfrag(&Bs[(wn * 64 + j * 16 + m) * 64 +
                            ((kk * 32 + quad * 8) ^ rsw)]);
#pragma unroll
      for (int i = 0; i < 4; ++i)
#pragma unroll
        for (int j = 0; j < 4; ++j)
          acc[i][j] = __builtin_amdgcn_mfma_f32_16x16x32_bf16(af[i], bfr[j],
                                                              acc[i][j], 0, 0, 0);
    }
    __syncthreads();
  }
  float csum[4] = {0.f, 0.f, 0.f, 0.f};
#pragma unroll
  for (int i = 0; i < 4; ++i) {
    int grow0 = bm * 128 + wm * 64 + i * 16 + quad * 4;
    float rq[4] = {0.f, 0.f, 0.f, 0.f};
#pragma unroll
    for (int j = 0; j < 4; ++j) {
      int gcol = bn * 128 + wn * 64 + j * 16 + m;
      float bv = bias ? bias[gcol] : 0.f;
#pragma unroll
      for (int rr = 0; rr < 4; ++rr) {
        size_t idx = (size_t)(grow0 + rr) * N + gcol;
        float v = acc[i][j][rr] + bv;
        if (resf) v += resf[idx];
        if (outb) outb[idx] = f2bf(v);
        else      outf[idx] = v;
        if (outb2) outb2[idx] = f2bf(v);
        if (colsum) csum[j] += v;
        if (rowssq) rq[rr] += v * v;
      }
    }
    if (rowssq) {
#pragma unroll
      for (int rr = 0; rr < 4; ++rr) {
        float s = rq[rr];
        s += __shfl_xor(s, 1); s += __shfl_xor(s, 2);
        s += __shfl_xor(s, 4); s += __shfl_xor(s, 8);
        if (m == 0) atomicAdd(rowssq + grow0 + rr, s);
      }
    }
  }
  if (colsum) {
    float* cs = (float*)As;   // reuse LDS (all reads done; barrier below)
    __syncthreads();
    if (tid < 128) cs[tid] = 0.f;
    __syncthreads();
    int lc = wn * 64 + m;
#pragma unroll
    for (int j = 0; j < 4; ++j) atomicAdd(&cs[lc + j * 16], csum[j]);
    __syncthreads();
    if (tid < 128) {
      int b = bm >> 2;
      atomicAdd(colsum + (size_t)b * 512 + bn * 128 + tid,
                cs[tid] * (1.f / 512.f));
    }
  }
}

// ---------------------------------------------------------------------------
// MLP1 fused (R8 body, 82us): out[M,2048] = silu(nh@W1g) * (nh@W1v), bf16,
// where nh = rms(h1). R19: consumes UN-normalized h1b; rms commutes with
// the gemm -> scale both accumulators by inv[row]=rsqrt(rssq/512+eps)
// BEFORE silu. 32KB LDS -> 5 blocks/CU (TLP carries the 2-barrier drain).
// ---------------------------------------------------------------------------
__global__ __launch_bounds__(256) void mlp1_k(const u16* __restrict__ A,
                                              const u16* __restrict__ W1T,
                                              const float* __restrict__ rssq,
                                              u16* __restrict__ out) {
  __shared__ u16 As[128 * 64];
  __shared__ u16 Bgs[64 * 64];
  __shared__ u16 Bvs[64 * 64];
  const int Kd = 512;
  int tid = threadIdx.x;
  int w = tid >> 6, lane = tid & 63;
  int m = lane & 15, quad = lane >> 4;
  int bm = blockIdx.x, bn = blockIdx.y;
  v4f accg[2][4] = {}, accv[2][4] = {};
  const int gswz = ((lane & 7) ^ (lane >> 3)) * 8;  // source-side swizzle
  const u16* Ag  = A + (size_t)(bm * 128 + w * 32 + (lane >> 3)) * Kd + gswz;
  const u16* Bgp = W1T + (size_t)(bn * 64 + w * 16 + (lane >> 3)) * Kd + gswz;
  const u16* Bvp = W1T + (size_t)(2048 + bn * 64 + w * 16 + (lane >> 3)) * Kd + gswz;
  u16* Al  = &As[w * 32 * 64];
  u16* Bgl = &Bgs[w * 16 * 64];
  u16* Bvl = &Bvs[w * 16 * 64];
  const int rsw = (m & 7) * 8;                      // read-side swizzle
  for (int k0 = 0; k0 < Kd; k0 += 64) {
#pragma unroll
    for (int it = 0; it < 4; ++it)
      async16(Ag + (size_t)it * 8 * Kd + k0, Al + it * 8 * 64);
#pragma unroll
    for (int it = 0; it < 2; ++it) {
      async16(Bgp + (size_t)it * 8 * Kd + k0, Bgl + it * 8 * 64);
      async16(Bvp + (size_t)it * 8 * Kd + k0, Bvl + it * 8 * 64);
    }
    __syncthreads();
#pragma unroll
    for (int kk = 0; kk < 2; ++kk) {
      v8bf af[2], bg[4], bv[4];
#pragma unroll
      for (int i = 0; i < 2; ++i)
        af[i] = ldfrag(&As[(w * 32 + i * 16 + m) * 64 +
                           ((kk * 32 + quad * 8) ^ rsw)]);
#pragma unroll
      for (int j = 0; j < 4; ++j) {
        bg[j] = ldfrag(&Bgs[(j * 16 + m) * 64 + ((kk * 32 + quad * 8) ^ rsw)]);
        bv[j] = ldfrag(&Bvs[(j * 16 + m) * 64 + ((kk * 32 + quad * 8) ^ rsw)]);
      }
#pragma unroll
      for (int i = 0; i < 2; ++i)
#pragma unroll
        for (int j = 0; j < 4; ++j) {
          accg[i][j] = __builtin_amdgcn_mfma_f32_16x16x32_bf16(af[i], bg[j],
                                                               accg[i][j], 0, 0, 0);
          accv[i][j] = __builtin_amdgcn_mfma_f32_16x16x32_bf16(af[i], bv[j],
                                                               accv[i][j], 0, 0, 0);
        }
    }
    __syncthreads();
  }
#pragma unroll
  for (int i = 0; i < 2; ++i) {
    int grow0 = bm * 128 + w * 32 + i * 16 + quad * 4;
    float inv[4];
#pragma unroll
    for (int rr = 0; rr < 4; ++rr)
      inv[rr] = rsqrtf(rssq[grow0 + rr] * (1.f / 512.f) + 1e-6f);
#pragma unroll
    for (int j = 0; j < 4; ++j) {
      int gcol = bn * 64 + j * 16 + m;
#pragma unroll
      for (int rr = 0; rr < 4; ++rr) {
        float g = accg[i][j][rr] * inv[rr];
        float sv = g / (1.f + __expf(-g));
        out[(size_t)(grow0 + rr) * 2048 + gcol] =
            f2bf(sv * (accv[i][j][rr] * inv[rr]));
      }
    }
  }
}

// ---------------------------------------------------------------------------
// Flash attention with fused RoPE (table-based), one block (1024 thr = 16
// waves) per (b,h). Reads fused qkv (stride 1536: q@0, k@512, v@1024).
// RoPE applied on Q-fragment load and K->LDS staging (4 pairs per uint4).
// V staging vectorized (uint4 global loads, 8 u16 LDS scatter stores).
// K and V^T LDS resident (swizzled). Wave w handles qt = w and 31-w.
// Paired S-tiles; dense K=32 PV. setprio around MFMA clusters (T5).
// ---------------------------------------------------------------------------
__global__ __launch_bounds__(1024) void attn_k(const u16* __restrict__ qkv,
                                               const float* __restrict__ tbl,
                                               u16* __restrict__ og) {
  __shared__ u16 Ks[512 * 64];
  __shared__ u16 Vt[64 * 512];
  __shared__ u16 Ps[16][16 * 40];
  int tid = threadIdx.x;
  int w = tid >> 6, lane = tid & 63;
  int m = lane & 15, quad = lane >> 4;
  int bh = blockIdx.x;
  int b = bh >> 3, h = bh & 7;
  const size_t qbase = (size_t)b * 512 * 1536 + h * 64;
  const size_t obase = (size_t)b * 512 * 512 + h * 64;
  const u16* kbase = qkv + (size_t)b * 512 * 1536 + 512 + h * 64;
  const u16* vbase = kbase + 512;

  {
    int d8 = (tid & 7) * 8;
    for (int s = tid >> 3; s < 512; s += 128) {
      uint4 t4 = *(const uint4*)(kbase + (size_t)s * 1536 + d8);
      const float4* tp = (const float4*)(tbl + s * 64 + d8);
      float4 cs01 = tp[0], cs23 = tp[1];
      t4.x = rot1(t4.x, cs01.x, cs01.y);
      t4.y = rot1(t4.y, cs01.z, cs01.w);
      t4.z = rot1(t4.z, cs23.x, cs23.y);
      t4.w = rot1(t4.w, cs23.z, cs23.w);
      *(uint4*)&Ks[s * 64 + (d8 ^ ((s & 7) * 8))] = t4;
    }
  }
  {
    int d0 = (tid & 7) * 8;
    for (int s = tid >> 3; s < 512; s += 128) {
      uint4 v4 = *(const uint4*)(vbase + (size_t)s * 1536 + d0);
      const u16* vv = (const u16*)&v4;
#pragma unroll
      for (int j = 0; j < 8; ++j) {
        int d = d0 + j;
        Vt[d * 512 + (s ^ ((d & 7) * 8))] = vv[j];
      }
    }
  }
  __syncthreads();

  for (int rep = 0; rep < 2; ++rep) {
    int qt = rep == 0 ? w : 31 - w;
    int tb = qt * 16;
    const u16* qp = qkv + qbase + (size_t)(tb + m) * 1536;
    uint4 q0 = *(const uint4*)(qp + quad * 8);
    uint4 q1 = *(const uint4*)(qp + 32 + quad * 8);
    {
      const float* tq = tbl + (tb + m) * 64;
      float4 a = *(const float4*)(tq + quad * 8);
      float4 b4 = *(const float4*)(tq + quad * 8 + 4);
      q0.x = rot1(q0.x, a.x, a.y);   q0.y = rot1(q0.y, a.z, a.w);
      q0.z = rot1(q0.z, b4.x, b4.y); q0.w = rot1(q0.w, b4.z, b4.w);
      float4 c4 = *(const float4*)(tq + 32 + quad * 8);
      float4 d4 = *(const float4*)(tq + 36 + quad * 8);
      q1.x = rot1(q1.x, c4.x, c4.y); q1.y = rot1(q1.y, c4.z, c4.w);
      q1.z = rot1(q1.z, d4.x, d4.y); q1.w = rot1(q1.w, d4.z, d4.w);
    }
    v8bf aq0 = __builtin_bit_cast(v8bf, q0);
    v8bf aq1 = __builtin_bit_cast(v8bf, q1);
    v4f acc[4] = {};
    float mr[4], lr_[4];
#pragma unroll
    for (int rr = 0; rr < 4; ++rr) { mr[rr] = -1.0e30f; lr_[rr] = 0.f; }
    int swz = (m & 7) * 8;

    for (int st2 = 0; st2 <= qt; st2 += 2) {
      int srA = st2 * 16 + m;
      v8bf ka0 = ldfrag(&Ks[srA * 64 + ((quad * 8) ^ swz)]);
      v8bf ka1 = ldfrag(&Ks[srA * 64 + ((32 + quad * 8) ^ swz)]);
      v4f s4a = {};
      __builtin_amdgcn_s_setprio(1);
      s4a = __builtin_amdgcn_mfma_f32_16x16x32_bf16(aq0, ka0, s4a, 0, 0, 0);
      s4a = __builtin_amdgcn_mfma_f32_16x16x32_bf16(aq1, ka1, s4a, 0, 0, 0);
      __builtin_amdgcn_s_setprio(0);
      bool haveB = (st2 + 1 <= qt);
      v4f s4b = {};
      if (haveB) {
        int srB = srA + 16;
        v8bf kb0 = ldfrag(&Ks[srB * 64 + ((quad * 8) ^ swz)]);
        v8bf kb1 = ldfrag(&Ks[srB * 64 + ((32 + quad * 8) ^ swz)]);
        __builtin_amdgcn_s_setprio(1);
        s4b = __builtin_amdgcn_mfma_f32_16x16x32_bf16(aq0, kb0, s4b, 0, 0, 0);
        s4b = __builtin_amdgcn_mfma_f32_16x16x32_bf16(aq1, kb1, s4b, 0, 0, 0);
        __builtin_amdgcn_s_setprio(0);
      }
      float sca[4], scb[4];
#pragma unroll
      for (int rr = 0; rr < 4; ++rr) {
        int rowt = tb + quad * 4 + rr;
        sca[rr] = s4a[rr] * 0.125f;
        if (st2 == qt && st2 * 16 + m > rowt) sca[rr] = -1.0e9f;
        scb[rr] = haveB ? s4b[rr] * 0.125f : -1.0e30f;
        if (haveB && st2 + 1 == qt && (st2 + 1) * 16 + m > rowt) scb[rr] = -1.0e9f;
      }
      float pva[4], pvb[4], alpha[4];
#pragma unroll
      for (int rr = 0; rr < 4; ++rr) {
        float v = fmaxf(sca[rr], scb[rr]);
        v = fmaxf(v, __shfl_xor(v, 1));
        v = fmaxf(v, __shfl_xor(v, 2));
        v = fmaxf(v, __shfl_xor(v, 4));
        v = fmaxf(v, __shfl_xor(v, 8));
        float mn = fmaxf(mr[rr], v);
        alpha[rr] = __expf(mr[rr] - mn);
        pva[rr] = __expf(sca[rr] - mn);
        pvb[rr] = __expf(scb[rr] - mn);
        mr[rr] = mn;
      }
#pragma unroll
      for (int rr = 0; rr < 4; ++rr) {
        float s = pva[rr] + pvb[rr];
        s += __shfl_xor(s, 1); s += __shfl_xor(s, 2);
        s += __shfl_xor(s, 4); s += __shfl_xor(s, 8);
        lr_[rr] = lr_[rr] * alpha[rr] + s;
#pragma unroll
        for (int c = 0; c < 4; ++c) acc[c][rr] *= alpha[rr];
        Ps[w][(quad * 4 + rr) * 40 + m]      = f2bf(pva[rr]);
        Ps[w][(quad * 4 + rr) * 40 + 16 + m] = f2bf(pvb[rr]);
      }
      __asm__ volatile("" ::: "memory");  // keep P stores before frag reads
      v8bf pf = ldfrag(&Ps[w][m * 40 + quad * 8]);
      __builtin_amdgcn_s_setprio(1);
#pragma unroll
      for (int c = 0; c < 4; ++c) {
        int drow = c * 16 + m;
        v8bf vf = ldfrag(&Vt[drow * 512 +
                             ((st2 * 16 + quad * 8) ^ ((drow & 7) * 8))]);
        acc[c] = __builtin_amdgcn_mfma_f32_16x16x32_bf16(pf, vf, acc[c], 0, 0, 0);
      }
      __builtin_amdgcn_s_setprio(0);
    }
#pragma unroll
    for (int rr = 0; rr < 4; ++rr) {
      int t = tb + quad * 4 + rr;
      float inv = 1.f / lr_[rr];
      u16* op = og + obase + (size_t)t * 512;
#pragma unroll
      for (int c = 0; c < 4; ++c) op[c * 16 + m] = f2bf(acc[c][rr] * inv);
    }
  }
}

// ---------------------------------------------------------------------------
// Batched GEMV: wkey/wval/abase/ws per batch. grid (25, 32).
// ---------------------------------------------------------------------------
__global__ __launch_bounds__(256) void gemv_k(
    const float* __restrict__ qw_g, const float* __restrict__ Wwk,
    const float* __restrict__ bwk, const float* __restrict__ Wwv,
    const float* __restrict__ bwv, const float* __restrict__ Wg1,
    const float* __restrict__ bg1, const float* __restrict__ Wws,
    const float* __restrict__ bws, float* __restrict__ wkey_g,
    float* __restrict__ wval_g, float* __restrict__ abase_g,
    float* __restrict__ ws_g) {
  __shared__ float qs[512];
  __shared__ float prt[4][64];
  __shared__ float sred[8];
  int tid = threadIdx.x;
  int b = blockIdx.y, cg = blockIdx.x;
  qs[tid]       = qw_g[(size_t)b * 512 + tid];
  qs[tid + 256] = qw_g[(size_t)b * 512 + tid + 256];
  __syncthreads();
  if (cg == 24) {
    float p = qs[tid] * Wws[tid] + qs[tid + 256] * Wws[tid + 256];
    float tot = block_sum256(p, sred);
    if (tid == 0) {
      float wsv = 1.f / (1.f + __expf(-(tot + bws[0])));
      ws_g[b] = fminf(fmaxf(wsv, 0.f), 1.f);
    }
    return;
  }
  int sel = cg >> 3;
  int c0 = (cg & 7) * 64;
  const float* W = sel == 0 ? Wwk : (sel == 1 ? Wwv : Wg1);
  const float* bias = sel == 0 ? bwk : (sel == 1 ? bwv : bg1);
  float* dst = sel == 0 ? wkey_g : (sel == 1 ? wval_g : abase_g);
  int kg = tid >> 6, cl = tid & 63;
  const float* Wp = W + (size_t)(kg * 128) * 512 + c0 + cl;
  float acc = 0.f;
#pragma unroll 8
  for (int i = 0; i < 128; ++i) acc += qs[kg * 128 + i] * Wp[(size_t)i * 512];
  prt[kg][cl] = acc;
  __syncthreads();
  if (tid < 64)
    dst[(size_t)b * 512 + c0 + tid] =
        prt[0][tid] + prt[1][tid] + prt[2][tid] + prt[3][tid] + bias[c0 + tid];
}

// ---------------------------------------------------------------------------
// Episodic memory rest + gate, one block (256 thr) per batch element.
// ---------------------------------------------------------------------------
__global__ __launch_bounds__(256) void epi2_k(
    const float* __restrict__ qw_g, const float* __restrict__ wkey_g,
    const float* __restrict__ wval_g, const float* __restrict__ abase_g,
    const float* __restrict__ ws_g, const float* __restrict__ keys,
    const float* __restrict__ vals, const float* __restrict__ age,
    const float* __restrict__ strength, const float* __restrict__ Wg1,
    const float* __restrict__ Wg2, const float* __restrict__ bg2,
    const float* __restrict__ rms_read, float* __restrict__ read_f,
    float* __restrict__ gate_f, float* __restrict__ keys_out,
    float* __restrict__ vals_out, float* __restrict__ age_out,
    float* __restrict__ sn_out, float* __restrict__ gate_out) {
  int b = blockIdx.x;
  int tid = threadIdx.x;
  int w = tid >> 6, lane = tid & 63;
  __shared__ float qs[512], wkl[512], wvl[512];
  __shared__ float knorm[64], sr[64], swv[64], wread[64];
  __shared__ float sred[8];
  __shared__ float scal[2];
  __shared__ int bestk;
  __shared__ float novs;

  qs[tid]        = qw_g[(size_t)b * 512 + tid];
  qs[tid + 256]  = qw_g[(size_t)b * 512 + tid + 256];
  wkl[tid]       = wkey_g[(size_t)b * 512 + tid];
  wkl[tid + 256] = wkey_g[(size_t)b * 512 + tid + 256];
  wvl[tid]       = wval_g[(size_t)b * 512 + tid];
  wvl[tid + 256] = wval_g[(size_t)b * 512 + tid + 256];
  __syncthreads();
  float ws_s = ws_g[b];
  float p = qs[tid] * qs[tid] + qs[tid + 256] * qs[tid + 256];
  float tot = block_sum256(p, sred);
  if (tid == 0) scal[0] = 1.f / (sqrtf(tot) + 1e-6f);
  p = wkl[tid] * wkl[tid] + wkl[tid + 256] * wkl[tid + 256];
  tot = block_sum256(p, sred);
  if (tid == 0) scal[1] = 1.f / (sqrtf(tot) + 1e-6f);
  __syncthreads();
  float qscale = scal[0], wscale = scal[1];
  for (int k = w; k < 64; k += 4) {
    float kf[8];
    ld8f(keys + ((size_t)b * 64 + k) * 512 + lane * 8, kf);
    float s2 = 0.f, sq = 0.f, sw = 0.f;
#pragma unroll
    for (int i = 0; i < 8; ++i) {
      s2 += kf[i] * kf[i];
      sq += kf[i] * qs[lane * 8 + i];
      sw += kf[i] * wkl[lane * 8 + i];
    }
    s2 = wave_sum64(s2);
    sq = wave_sum64(sq);
    sw = wave_sum64(sw);
    if (lane == 0) {
      float kn = sqrtf(s2) + 1e-6f;
      knorm[k] = kn;
      float st = strength[b * 64 + k];
      float ag = age[b * 64 + k];
      sr[k] = (sq * qscale) / kn + 0.5f * logf(fminf(fmaxf(st, 0.001f), 1e9f)) -
              0.02f * ag + ((st > 0.001f) ? 0.f : -1000.f);
      swv[k] = (sw * wscale) / kn;
    }
  }
  __syncthreads();
  if (w == 0) {
    float v = sr[lane];
    float mx = v;
    mx = fmaxf(mx, __shfl_xor(mx, 1));  mx = fmaxf(mx, __shfl_xor(mx, 2));
    mx = fmaxf(mx, __shfl_xor(mx, 4));  mx = fmaxf(mx, __shfl_xor(mx, 8));
    mx = fmaxf(mx, __shfl_xor(mx, 16)); mx = fmaxf(mx, __shfl_xor(mx, 32));
    float e = __expf(v - mx);
    float sm = wave_sum64(e);
    wread[lane] = e / sm;
  } else if (w == 1) {
    float v = swv[lane];
    int idx = lane;
#pragma unroll
    for (int mm = 1; mm < 64; mm <<= 1) {
      float ov = __shfl_xor(v, mm);
      int oi = __shfl_xor(idx, mm);
      if (ov > v || (ov == v && oi < idx)) { v = ov; idx = oi; }
    }
    if (lane == 0) { bestk = idx; novs = 1.f - v; }
  }
  __syncthreads();
  float rv0 = 0.f, rv1 = 0.f;
  for (int k = 0; k < 64; ++k) {
    float wr = wread[k];
    const float* vp = vals + ((size_t)b * 64 + k) * 512;
    rv0 += wr * vp[tid];
    rv1 += wr * vp[tid + 256];
  }
  p = rv0 * rv0 + rv1 * rv1;
  tot = block_sum256(p, sred);
  float rinv = rsqrtf(tot * (1.f / 512.f) + 1e-6f);
  read_f[(size_t)b * 512 + tid]       = rv0 * rinv * rms_read[tid];
  read_f[(size_t)b * 512 + tid + 256] = rv1 * rinv * rms_read[tid + 256];
  if (tid < 64) {
    int k = tid;
    float hard = (k == bestk) ? 1.f : 0.f;
    float ag = age[b * 64 + k];
    age_out[b * 64 + k] = (ag + 1.f) * (1.f - hard);
    float st = strength[b * 64 + k];
    float s0 = st * 0.995f;
    float snv = s0 + hard * ws_s * (1.f - s0);
    sn_out[b * 64 + k] = fminf(fmaxf(snv, 0.001f), 1.f);
  }
  for (int k = w; k < 64; k += 4) {
    float re = (k == bestk) ? ws_s * 0.5f : 0.f;
    float kf[8], vf[8];
    ld8f(keys + ((size_t)b * 64 + k) * 512 + lane * 8, kf);
    ld8f(vals + ((size_t)b * 64 + k) * 512 + lane * 8, vf);
    float u[8], ss = 0.f;
#pragma unroll
    for (int i = 0; i < 8; ++i) {
      u[i] = (1.f - re) * kf[i] + re * wkl[lane * 8 + i];
      ss += u[i] * u[i];
    }
    ss = wave_sum64(ss);
    float uinv = 1.f / (sqrtf(ss) + 1e-6f);
    float ko[8], vo[8];
#pragma unroll
    for (int i = 0; i < 8; ++i) {
      ko[i] = u[i] * uinv;
      vo[i] = (1.f - re) * vf[i] + re * wvl[lane * 8 + i];
    }
    st8f(keys_out + ((size_t)b * 64 + k) * 512 + lane * 8, ko);
    st8f(vals_out + ((size_t)b * 64 + k) * 512 + lane * 8, vo);
  }
  __syncthreads();
  float nov = novs;
  float a0 = abase_g[(size_t)b * 512 + tid] +
             ws_s * Wg1[(size_t)512 * 512 + tid] +
             nov * Wg1[(size_t)513 * 512 + tid];
  float a1 = abase_g[(size_t)b * 512 + tid + 256] +
             ws_s * Wg1[(size_t)512 * 512 + tid + 256] +
             nov * Wg1[(size_t)513 * 512 + tid + 256];
  float h0 = a0 / (1.f + __expf(-a0));
  float h1v = a1 / (1.f + __expf(-a1));
  float gp = h0 * Wg2[tid] + h1v * Wg2[tid + 256];
  tot = block_sum256(gp, sred);
  if (tid == 0) {
    float g = 1.f / (1.f + __expf(-(tot + bg2[0])));
    gate_f[b] = g;
    gate_out[b] = g;
  }
}

// ---------------------------------------------------------------------------
// out = h2 + gate[b] * read[b, d]   (f32 in, f32 out)
// ---------------------------------------------------------------------------
__global__ __launch_bounds__(256) void final_k(const float* __restrict__ h2,
                                               const float* __restrict__ read_f,
                                               const float* __restrict__ gate_f,
                                               float* __restrict__ outp) {
  size_t i2 = ((size_t)blockIdx.x * 256 + threadIdx.x) * 2;
  int b = (int)(i2 >> 18);
  int d = (int)(i2 & 511);
  float g = gate_f[b];
  float2 h = *(const float2*)(h2 + i2);
  outp[i2]     = h.x + g * read_f[b * 512 + d];
  outp[i2 + 1] = h.y + g * read_f[b * 512 + d + 1];
}

// ---------------------------------------------------------------------------
extern "C" void kernel_launch(void* const* d_in, const int* in_sizes, int n_in,
                              void* d_out, int out_size, void* d_ws,
                              size_t ws_size, hipStream_t stream) {
  const float* x        = (const float*)d_in[0];
  const float* epi_keys = (const float*)d_in[1];
  const float* epi_vals = (const float*)d_in[2];
  const float* epi_age  = (const float*)d_in[3];
  const float* epi_str  = (const float*)d_in[4];
  const int*   pos      = (const int*)d_in[5];
  const float* rms1     = (const float*)d_in[6];
  const float* rms_kv   = (const float*)d_in[7];
  const float* rms2     = (const float*)d_in[8];
  const float* rms_read = (const float*)d_in[9];
  const float* Wq = (const float*)d_in[10]; const float* bq = (const float*)d_in[11];
  const float* Wk = (const float*)d_in[12]; const float* bk = (const float*)d_in[13];
  const float* Wv = (const float*)d_in[14]; const float* bv = (const float*)d_in[15];
  const float* Wo = (const float*)d_in[16]; const float* bo = (const float*)d_in[17];
  const float* W1 = (const float*)d_in[18]; const float* W2 = (const float*)d_in[19];
  const float* Wwk = (const float*)d_in[20]; const float* bwk = (const float*)d_in[21];
  const float* Wwv = (const float*)d_in[22]; const float* bwv = (const float*)d_in[23];
  const float* Wws = (const float*)d_in[24]; const float* bws = (const float*)d_in[25];
  const float* Wg1 = (const float*)d_in[26]; const float* bg1 = (const float*)d_in[27];
  const float* Wg2 = (const float*)d_in[28]; const float* bg2 = (const float*)d_in[29];

  float* out      = (float*)d_out;
  float* out_main = out;
  float* out_keys = out + 8388608;
  float* out_vals = out + 9437184;
  float* out_age  = out + 10485760;
  float* out_sn   = out + 10487808;
  float* out_gate = out + 10489856;

  char* w8 = (char*)d_ws;
  size_t off = 0;
  auto alloc = [&](size_t bytes) {
    char* pp = w8 + off;
    off += (bytes + 255) & ~(size_t)255;
    return pp;
  };
  u16* WTqkv = (u16*)alloc((size_t)1536 * 512 * 2);  // [WTq ; WTk ; WTv]
  u16* WTo   = (u16*)alloc(512 * 512 * 2);
  u16* WT1   = (u16*)alloc((size_t)4096 * 512 * 2);
  u16* WT2   = (u16*)alloc((size_t)512 * 2048 * 2);
  const size_t TB = (size_t)16384 * 512 * 2;  // 16 MB bf16 tensor
  u16* nrm  = (u16*)alloc(TB);           // | gact (64 MB) overlays nrm+qkvb
  u16* qkvb = (u16*)alloc(3 * TB);       // | [16384][1536]
  u16* ob   = (u16*)alloc(TB);           // | h2f (32 MB f32) overlays ob+h1b
  u16* h1b  = (u16*)alloc(TB);           // | bf16 h1 (un-normalized)
  float* h1f = (float*)alloc((size_t)16384 * 512 * 4);
  u16*   gact = nrm;
  float* h2f  = (float*)ob;
  float* bias_qkv = (float*)alloc(1536 * 4);
  float* tbl      = (float*)alloc((size_t)512 * 64 * 4);  // rope table
  float* qw_g     = (float*)alloc((size_t)32 * 512 * 4);
  float* rssq     = (float*)alloc((size_t)16384 * 4);     // per-row sum(h1^2)
  float* wkey_g   = (float*)alloc((size_t)32 * 512 * 4);
  float* wval_g   = (float*)alloc((size_t)32 * 512 * 4);
  float* abase_g  = (float*)alloc((size_t)32 * 512 * 4);
  float* ws_g     = (float*)alloc(64 * 4);
  float* read_f   = (float*)alloc((size_t)32 * 512 * 4);
  float* gate_f   = (float*)alloc(64 * 4);

  // prep: transposes + bias concat + rope table + qw_g/rssq zero + rms(x->nrm)
  prep_k<<<8390, 256, 0, stream>>>(Wq, Wk, Wv, Wo, W1, W2, rms1, rms_kv, rms2,
                                   WTqkv, WTo, WT1, WT2, bq, bk, bv, bias_qkv,
                                   pos, tbl, qw_g, rssq, x, nrm);
  // fused Q|K|V projection (N=1536)
  gemm128_k<<<dim3(128, 12), 256, 0, stream>>>(nrm, WTqkv, bias_qkv, nullptr,
                                               qkvb, nullptr, nullptr, nullptr,
                                               nullptr, 1536, 512);
  // attention (rope fused via table)
  attn_k<<<256, 1024, 0, stream>>>(qkvb, tbl, ob);
  // output projection + residual: h1f (f32) + h1b (bf16) + per-row ssq
  gemm128_k<<<dim3(128, 4), 256, 0, stream>>>(ob, WTo, bo, x,
                                              nullptr, h1f, h1b, rssq,
                                              nullptr, 512, 512);
  // MLP1 (rms fused: consumes h1b + rssq)
  mlp1_k<<<dim3(128, 32), 256, 0, stream>>>(h1b, WT1, rssq, gact);
  // MLP2 + residual; column-sum fused into epilogue -> qw_g
  gemm128_k<<<dim3(128, 4), 256, 0, stream>>>(gact, WT2, nullptr, h1f,
                                              nullptr, h2f, nullptr, nullptr,
                                              qw_g, 512, 2048);
  // episodic memory + gate
  gemv_k<<<dim3(25, 32), 256, 0, stream>>>(qw_g, Wwk, bwk, Wwv, bwv, Wg1, bg1,
                                           Wws, bws, wkey_g, wval_g, abase_g, ws_g);
  epi2_k<<<32, 256, 0, stream>>>(qw_g, wkey_g, wval_g, abase_g, ws_g, epi_keys,
                                 epi_vals, epi_age, epi_str, Wg1, Wg2, bg2,
                                 rms_read, read_f, gate_f, out_keys, out_vals,
                                 out_age, out_sn, out_gate);
  // final broadcast add
  final_k<<<16384, 256, 0, stream>>>(h2f, read_f, gate_f, out_main);
}

// Round 13
// 488.204 us; speedup vs baseline: 1.0381x; 1.0381x over previous
//
#include <hip/hip_runtime.h>

// ---------------------------------------------------------------------------
// CWRRTEWindowCell on MI355X (gfx950). FP32 I/O, bf16 MFMA internals.
// B=32, W=T=512, D=512, H=8, DH=64, K=64.
// R20: FINAL consolidation = exact R18/R16 config (best verified: 498.8 /
// 502.9 us). R19's algebraic rms-fusion reverted: mlp1 epilogue rsqrt+loads
// (+4.5% real) + Wo-gemm h1b store/atomics consumed the rms_k saving.
// Constraint ledger: the 2-barrier GEMM structure is the binding limit
// (MfmaUtil ~36% = ~92% of its documented ceiling; HBM 22% — neither HW
// roofline). Exit would be the 8-phase counted-vmcnt port (1.7x on GEMM
// elsewhere) but needs A/B + race screening unavailable here; 5 structure
// attempts (R9,R10,R11,R15,R17) all regressed and were reverted.
// Net session wins: R8 T2 XOR-swizzle (conflicts 3.1e7->0, -63us),
// R12 QKV-fused gemm + launch fusion (-26us), R13/R14 rope-as-table in
// attn + prep mega-kernel (-19us). 605 -> ~500 us.
// ---------------------------------------------------------------------------

#define DEVI __device__ __forceinline__
typedef unsigned short u16;
typedef unsigned int   u32;
typedef __bf16 v8bf __attribute__((ext_vector_type(8)));
typedef float  v4f  __attribute__((ext_vector_type(4)));

DEVI float bf2f(u16 u) { u32 v = ((u32)u) << 16; return __builtin_bit_cast(float, v); }
DEVI u16 f2bf(float f) {
  u32 x = __builtin_bit_cast(u32, f);
  u32 r = x + 0x7fffu + ((x >> 16) & 1u);
  return (u16)(r >> 16);
}
DEVI uint4 pack8(const float* f) {
  u32 a[4];
#pragma unroll
  for (int i = 0; i < 4; ++i)
    a[i] = (u32)f2bf(f[2*i]) | ((u32)f2bf(f[2*i+1]) << 16);
  uint4 v; v.x = a[0]; v.y = a[1]; v.z = a[2]; v.w = a[3]; return v;
}
DEVI void ld8f(const float* p, float* f) {
  float4 a = *(const float4*)p, b = *(const float4*)(p + 4);
  f[0]=a.x; f[1]=a.y; f[2]=a.z; f[3]=a.w; f[4]=b.x; f[5]=b.y; f[6]=b.z; f[7]=b.w;
}
DEVI void st8f(float* p, const float* f) {
  *(float4*)p       = make_float4(f[0], f[1], f[2], f[3]);
  *(float4*)(p + 4) = make_float4(f[4], f[5], f[6], f[7]);
}
DEVI v8bf ldfrag(const u16* p) { return __builtin_bit_cast(v8bf, *(const uint4*)p); }

// rotate one (even,odd) bf16 pair packed in a u32 by (c,s)
DEVI u32 rot1(u32 w, float c, float s) {
  float e = bf2f((u16)(w & 0xffffu)), o = bf2f((u16)(w >> 16));
  float ne = e * c - o * s;
  float no = e * s + o * c;
  return (u32)f2bf(ne) | ((u32)f2bf(no) << 16);
}

// async global->LDS, 16B per lane; lds dest wave-uniform base + lane*16.
DEVI void async16(const u16* g, u16* l) {
  __builtin_amdgcn_global_load_lds(
      (const __attribute__((address_space(1))) void*)g,
      (__attribute__((address_space(3))) void*)l, 16, 0, 0);
}

DEVI float wave_sum64(float v) {
  v += __shfl_xor(v, 1);  v += __shfl_xor(v, 2);  v += __shfl_xor(v, 4);
  v += __shfl_xor(v, 8);  v += __shfl_xor(v, 16); v += __shfl_xor(v, 32);
  return v;
}

__device__ float block_sum256(float v, float* sred) {
  v = wave_sum64(v);
  int w = threadIdx.x >> 6;
  __syncthreads();
  if ((threadIdx.x & 63) == 0) sred[w] = v;
  __syncthreads();
  return sred[0] + sred[1] + sred[2] + sred[3];
}

// ---------------------------------------------------------------------------
// PREP mega-kernel. Block-range decode:
//   [0,256)     Wq -> WTqkv rows 0-511     (scale rms1)
//   [256,512)   Wk -> WTqkv rows 512-1023  (scale rms_kv)
//   [512,768)   Wv -> WTqkv rows 1024-1535 (scale rms_kv)
//   [768,1024)  Wo -> WTo
//   [1024,3072) W1 -> WT1 (scale rms2)
//   [3072,4096) W2 -> WT2
//   [4096,4102) bias_qkv = [bq|bk|bv]
//   [4102,4166) rope table tbl[t][f] = {cos,sin}(pos[t]*10000^(-2f/64))
//   [4166,4230) qw_g = 0 (atomic accumulator, re-zeroed each replay)
//   [4230,8326) RMSNorm x -> nrm (bf16)
// ---------------------------------------------------------------------------
__global__ __launch_bounds__(256) void prep_k(
    const float* __restrict__ Wq, const float* __restrict__ Wk,
    const float* __restrict__ Wv, const float* __restrict__ Wo,
    const float* __restrict__ W1, const float* __restrict__ W2,
    const float* __restrict__ rms1, const float* __restrict__ rms_kv,
    const float* __restrict__ rms2, u16* __restrict__ WTqkv,
    u16* __restrict__ WTo, u16* __restrict__ WT1, u16* __restrict__ WT2,
    const float* __restrict__ bq, const float* __restrict__ bk,
    const float* __restrict__ bv, float* __restrict__ bias_qkv,
    const int* __restrict__ pos, float* __restrict__ tbl,
    float* __restrict__ qw_g, const float* __restrict__ x,
    u16* __restrict__ nrm) {
  int id = blockIdx.x;
  int tid = threadIdx.x;
  if (id >= 4230) {  // RMSNorm
    int w = tid >> 6, lane = tid & 63;
    size_t row = (size_t)(id - 4230) * 4 + w;
    float xf[8]; ld8f(x + row * 512 + lane * 8, xf);
    float ss = 0.f;
#pragma unroll
    for (int i = 0; i < 8; ++i) ss += xf[i] * xf[i];
    ss = wave_sum64(ss);
    float inv = rsqrtf(ss * (1.f / 512.f) + 1e-6f);
    float of[8];
#pragma unroll
    for (int i = 0; i < 8; ++i) of[i] = xf[i] * inv;
    *(uint4*)(nrm + row * 512 + lane * 8) = pack8(of);
    return;
  }
  if (id >= 4166) {  // zero qw_g
    qw_g[(id - 4166) * 256 + tid] = 0.f;
    return;
  }
  if (id >= 4102) {  // rope table
    int idx = (id - 4102) * 256 + tid;   // 0..16383
    int t = idx >> 5, f = idx & 31;
    float freq = exp2f(-0.41524101186f * (float)f);  // 10000^(-2f/64)
    float ang = (float)pos[t] * freq;
    float sv, cv;
    sincosf(ang, &sv, &cv);
    tbl[t * 64 + f * 2]     = cv;
    tbl[t * 64 + f * 2 + 1] = sv;
    return;
  }
  if (id >= 4096) {  // bias concat
    int j = (id - 4096) * 256 + tid;
    bias_qkv[j] = j < 512 ? bq[j] : (j < 1024 ? bk[j - 512] : bv[j - 1024]);
    return;
  }
  const float* in; const float* scale; u16* outp; int R, C, bx, by;
  if (id < 256)       { in=Wq; scale=rms1;   outp=WTqkv;            R=512;  C=512;  int l=id;       bx=l&15;  by=l>>4; }
  else if (id < 512)  { in=Wk; scale=rms_kv; outp=WTqkv+512*512;    R=512;  C=512;  int l=id-256;   bx=l&15;  by=l>>4; }
  else if (id < 768)  { in=Wv; scale=rms_kv; outp=WTqkv+1024*512;   R=512;  C=512;  int l=id-512;   bx=l&15;  by=l>>4; }
  else if (id < 1024) { in=Wo; scale=nullptr;outp=WTo;              R=512;  C=512;  int l=id-768;   bx=l&15;  by=l>>4; }
  else if (id < 3072) { in=W1; scale=rms2;   outp=WT1;              R=512;  C=4096; int l=id-1024;  bx=l&127; by=l>>7; }
  else                { in=W2; scale=nullptr;outp=WT2;              R=2048; C=512;  int l=id-3072;  bx=l&15;  by=l>>4; }
  __shared__ u16 t[32][33];
  int c0 = bx * 32, r0 = by * 32;
  int lc = tid & 31, lr = tid >> 5;
  for (int rr = lr; rr < 32; rr += 8) {
    float v = in[(size_t)(r0 + rr) * C + c0 + lc];
    if (scale) v *= scale[r0 + rr];
    t[rr][lc] = f2bf(v);
  }
  __syncthreads();
  for (int rr = lr; rr < 32; rr += 8)
    outp[(size_t)(c0 + rr) * R + r0 + lc] = t[lc][rr];
}

// ---------------------------------------------------------------------------
// RMSNorm (standalone, for h1f -> n2).
// ---------------------------------------------------------------------------
__global__ __launch_bounds__(256) void rms_k(const float* __restrict__ x,
                                             u16* __restrict__ o1) {
  int w = threadIdx.x >> 6, lane = threadIdx.x & 63;
  size_t row = (size_t)blockIdx.x * 4 + w;
  float xf[8]; ld8f(x + row * 512 + lane * 8, xf);
  float ss = 0.f;
#pragma unroll
  for (int i = 0; i < 8; ++i) ss += xf[i] * xf[i];
  ss = wave_sum64(ss);
  float inv = rsqrtf(ss * (1.f / 512.f) + 1e-6f);
  float of[8];
#pragma unroll
  for (int i = 0; i < 8; ++i) of[i] = xf[i] * inv;
  *(uint4*)(o1 + row * 512 + lane * 8) = pack8(of);
}

// ---------------------------------------------------------------------------
// 128x128-tile GEMM (R8 body): A[M,Kd](bf16) @ BT[N][Kd](bf16).
// R8 swizzle: source column pre-swizzled (slot ^= row&7), read column XORs
// (m&7)*8. bias indexed by gcol (stacked bias for fused QKV).
// Optional colsum epilogue -> atomicAdd colsum[b*512+col]/512 (b=bm>>2;
// 128-row tiles never straddle a b boundary).
// ---------------------------------------------------------------------------
__global__ __launch_bounds__(256) void gemm128_k(const u16* __restrict__ A,
                                                 const u16* __restrict__ BT,
                                                 const float* __restrict__ bias,
                                                 const float* __restrict__ resf,
                                                 u16* __restrict__ outb,
                                                 float* __restrict__ outf,
                                                 float* __restrict__ colsum,
                                                 int N, int Kd) {
  __shared__ u16 As[128 * 64];
  __shared__ u16 Bs[128 * 64];
  int tid = threadIdx.x;
  int w = tid >> 6, lane = tid & 63;
  int m = lane & 15, quad = lane >> 4;
  int wm = w >> 1, wn = w & 1;
  int bm = blockIdx.x, bn = blockIdx.y;
  v4f acc[4][4] = {};
  const int gswz = ((lane & 7) ^ (lane >> 3)) * 8;  // source-side swizzle
  const u16* Ag = A + (size_t)(bm * 128 + w * 32 + (lane >> 3)) * Kd + gswz;
  const u16* Bg = BT + (size_t)(bn * 128 + w * 32 + (lane >> 3)) * Kd + gswz;
  u16* Al = &As[w * 32 * 64];
  u16* Bl = &Bs[w * 32 * 64];
  const int rsw = (m & 7) * 8;                      // read-side swizzle
  for (int k0 = 0; k0 < Kd; k0 += 64) {
#pragma unroll
    for (int it = 0; it < 4; ++it) {
      async16(Ag + (size_t)it * 8 * Kd + k0, Al + it * 8 * 64);
      async16(Bg + (size_t)it * 8 * Kd + k0, Bl + it * 8 * 64);
    }
    __syncthreads();
#pragma unroll
    for (int kk = 0; kk < 2; ++kk) {
      v8bf af[4], bfr[4];
#pragma unroll
      for (int i = 0; i < 4; ++i)
        af[i] = ldfrag(&As[(wm * 64 + i * 16 + m) * 64 +
                           ((kk * 32 + quad * 8) ^ rsw)]);
#pragma unroll
      for (int j = 0; j < 4; ++j)
        bfr[j] = ldfrag(&Bs[(wn * 64 + j * 16 + m) * 64 +
                            ((kk * 32 + quad * 8) ^ rsw)]);
#pragma unroll
      for (int i = 0; i < 4; ++i)
#pragma unroll
        for (int j = 0; j < 4; ++j)
          acc[i][j] = __builtin_amdgcn_mfma_f32_16x16x32_bf16(af[i], bfr[j],
                                                              acc[i][j], 0, 0, 0);
    }
    __syncthreads();
  }
  float csum[4] = {0.f, 0.f, 0.f, 0.f};
#pragma unroll
  for (int i = 0; i < 4; ++i) {
    int grow0 = bm * 128 + wm * 64 + i * 16 + quad * 4;
#pragma unroll
    for (int j = 0; j < 4; ++j) {
      int gcol = bn * 128 + wn * 64 + j * 16 + m;
      float bv = bias ? bias[gcol] : 0.f;
#pragma unroll
      for (int rr = 0; rr < 4; ++rr) {
        size_t idx = (size_t)(grow0 + rr) * N + gcol;
        float v = acc[i][j][rr] + bv;
        if (resf) v += resf[idx];
        if (outb) outb[idx] = f2bf(v);
        else      outf[idx] = v;
        if (colsum) csum[j] += v;
      }
    }
  }
  if (colsum) {
    float* cs = (float*)As;   // reuse LDS (all reads done; barrier below)
    __syncthreads();
    if (tid < 128) cs[tid] = 0.f;
    __syncthreads();
    int lc = wn * 64 + m;
#pragma unroll
    for (int j = 0; j < 4; ++j) atomicAdd(&cs[lc + j * 16], csum[j]);
    __syncthreads();
    if (tid < 128) {
      int b = bm >> 2;
      atomicAdd(colsum + (size_t)b * 512 + bn * 128 + tid,
                cs[tid] * (1.f / 512.f));
    }
  }
}

// ---------------------------------------------------------------------------
// MLP1 fused (R8 body, 82us): out[M,2048] = silu(A@W1g) * (A@W1v), bf16.
// Block = 128 rows x (64g+64v); 32KB LDS -> 5 blocks/CU (TLP carries the
// 2-barrier stage drain).
// ---------------------------------------------------------------------------
__global__ __launch_bounds__(256) void mlp1_k(const u16* __restrict__ A,
                                              const u16* __restrict__ W1T,
                                              u16* __restrict__ out) {
  __shared__ u16 As[128 * 64];
  __shared__ u16 Bgs[64 * 64];
  __shared__ u16 Bvs[64 * 64];
  const int Kd = 512;
  int tid = threadIdx.x;
  int w = tid >> 6, lane = tid & 63;
  int m = lane & 15, quad = lane >> 4;
  int bm = blockIdx.x, bn = blockIdx.y;
  v4f accg[2][4] = {}, accv[2][4] = {};
  const int gswz = ((lane & 7) ^ (lane >> 3)) * 8;  // source-side swizzle
  const u16* Ag  = A + (size_t)(bm * 128 + w * 32 + (lane >> 3)) * Kd + gswz;
  const u16* Bgp = W1T + (size_t)(bn * 64 + w * 16 + (lane >> 3)) * Kd + gswz;
  const u16* Bvp = W1T + (size_t)(2048 + bn * 64 + w * 16 + (lane >> 3)) * Kd + gswz;
  u16* Al  = &As[w * 32 * 64];
  u16* Bgl = &Bgs[w * 16 * 64];
  u16* Bvl = &Bvs[w * 16 * 64];
  const int rsw = (m & 7) * 8;                      // read-side swizzle
  for (int k0 = 0; k0 < Kd; k0 += 64) {
#pragma unroll
    for (int it = 0; it < 4; ++it)
      async16(Ag + (size_t)it * 8 * Kd + k0, Al + it * 8 * 64);
#pragma unroll
    for (int it = 0; it < 2; ++it) {
      async16(Bgp + (size_t)it * 8 * Kd + k0, Bgl + it * 8 * 64);
      async16(Bvp + (size_t)it * 8 * Kd + k0, Bvl + it * 8 * 64);
    }
    __syncthreads();
#pragma unroll
    for (int kk = 0; kk < 2; ++kk) {
      v8bf af[2], bg[4], bv[4];
#pragma unroll
      for (int i = 0; i < 2; ++i)
        af[i] = ldfrag(&As[(w * 32 + i * 16 + m) * 64 +
                           ((kk * 32 + quad * 8) ^ rsw)]);
#pragma unroll
      for (int j = 0; j < 4; ++j) {
        bg[j] = ldfrag(&Bgs[(j * 16 + m) * 64 + ((kk * 32 + quad * 8) ^ rsw)]);
        bv[j] = ldfrag(&Bvs[(j * 16 + m) * 64 + ((kk * 32 + quad * 8) ^ rsw)]);
      }
#pragma unroll
      for (int i = 0; i < 2; ++i)
#pragma unroll
        for (int j = 0; j < 4; ++j) {
          accg[i][j] = __builtin_amdgcn_mfma_f32_16x16x32_bf16(af[i], bg[j],
                                                               accg[i][j], 0, 0, 0);
          accv[i][j] = __builtin_amdgcn_mfma_f32_16x16x32_bf16(af[i], bv[j],
                                                               accv[i][j], 0, 0, 0);
        }
    }
    __syncthreads();
  }
#pragma unroll
  for (int i = 0; i < 2; ++i) {
    int grow0 = bm * 128 + w * 32 + i * 16 + quad * 4;
#pragma unroll
    for (int j = 0; j < 4; ++j) {
      int gcol = bn * 64 + j * 16 + m;
#pragma unroll
      for (int rr = 0; rr < 4; ++rr) {
        float g = accg[i][j][rr];
        float sv = g / (1.f + __expf(-g));
        out[(size_t)(grow0 + rr) * 2048 + gcol] = f2bf(sv * accv[i][j][rr]);
      }
    }
  }
}

// ---------------------------------------------------------------------------
// Flash attention with fused RoPE (table-based), one block (1024 thr = 16
// waves) per (b,h). Reads fused qkv (stride 1536: q@0, k@512, v@1024).
// RoPE applied on Q-fragment load and K->LDS staging (4 pairs per uint4).
// V staging vectorized (uint4 global loads, 8 u16 LDS scatter stores).
// K and V^T LDS resident (swizzled). Wave w handles qt = w and 31-w.
// Paired S-tiles; dense K=32 PV. setprio around MFMA clusters (T5).
// ---------------------------------------------------------------------------
__global__ __launch_bounds__(1024) void attn_k(const u16* __restrict__ qkv,
                                               const float* __restrict__ tbl,
                                               u16* __restrict__ og) {
  __shared__ u16 Ks[512 * 64];
  __shared__ u16 Vt[64 * 512];
  __shared__ u16 Ps[16][16 * 40];
  int tid = threadIdx.x;
  int w = tid >> 6, lane = tid & 63;
  int m = lane & 15, quad = lane >> 4;
  int bh = blockIdx.x;
  int b = bh >> 3, h = bh & 7;
  const size_t qbase = (size_t)b * 512 * 1536 + h * 64;
  const size_t obase = (size_t)b * 512 * 512 + h * 64;
  const u16* kbase = qkv + (size_t)b * 512 * 1536 + 512 + h * 64;
  const u16* vbase = kbase + 512;

  {
    int d8 = (tid & 7) * 8;
    for (int s = tid >> 3; s < 512; s += 128) {
      uint4 t4 = *(const uint4*)(kbase + (size_t)s * 1536 + d8);
      const float4* tp = (const float4*)(tbl + s * 64 + d8);
      float4 cs01 = tp[0], cs23 = tp[1];
      t4.x = rot1(t4.x, cs01.x, cs01.y);
      t4.y = rot1(t4.y, cs01.z, cs01.w);
      t4.z = rot1(t4.z, cs23.x, cs23.y);
      t4.w = rot1(t4.w, cs23.z, cs23.w);
      *(uint4*)&Ks[s * 64 + (d8 ^ ((s & 7) * 8))] = t4;
    }
  }
  {
    int d0 = (tid & 7) * 8;
    for (int s = tid >> 3; s < 512; s += 128) {
      uint4 v4 = *(const uint4*)(vbase + (size_t)s * 1536 + d0);
      const u16* vv = (const u16*)&v4;
#pragma unroll
      for (int j = 0; j < 8; ++j) {
        int d = d0 + j;
        Vt[d * 512 + (s ^ ((d & 7) * 8))] = vv[j];
      }
    }
  }
  __syncthreads();

  for (int rep = 0; rep < 2; ++rep) {
    int qt = rep == 0 ? w : 31 - w;
    int tb = qt * 16;
    const u16* qp = qkv + qbase + (size_t)(tb + m) * 1536;
    uint4 q0 = *(const uint4*)(qp + quad * 8);
    uint4 q1 = *(const uint4*)(qp + 32 + quad * 8);
    {
      const float* tq = tbl + (tb + m) * 64;
      float4 a = *(const float4*)(tq + quad * 8);
      float4 b4 = *(const float4*)(tq + quad * 8 + 4);
      q0.x = rot1(q0.x, a.x, a.y);   q0.y = rot1(q0.y, a.z, a.w);
      q0.z = rot1(q0.z, b4.x, b4.y); q0.w = rot1(q0.w, b4.z, b4.w);
      float4 c4 = *(const float4*)(tq + 32 + quad * 8);
      float4 d4 = *(const float4*)(tq + 36 + quad * 8);
      q1.x = rot1(q1.x, c4.x, c4.y); q1.y = rot1(q1.y, c4.z, c4.w);
      q1.z = rot1(q1.z, d4.x, d4.y); q1.w = rot1(q1.w, d4.z, d4.w);
    }
    v8bf aq0 = __builtin_bit_cast(v8bf, q0);
    v8bf aq1 = __builtin_bit_cast(v8bf, q1);
    v4f acc[4] = {};
    float mr[4], lr_[4];
#pragma unroll
    for (int rr = 0; rr < 4; ++rr) { mr[rr] = -1.0e30f; lr_[rr] = 0.f; }
    int swz = (m & 7) * 8;

    for (int st2 = 0; st2 <= qt; st2 += 2) {
      int srA = st2 * 16 + m;
      v8bf ka0 = ldfrag(&Ks[srA * 64 + ((quad * 8) ^ swz)]);
      v8bf ka1 = ldfrag(&Ks[srA * 64 + ((32 + quad * 8) ^ swz)]);
      v4f s4a = {};
      __builtin_amdgcn_s_setprio(1);
      s4a = __builtin_amdgcn_mfma_f32_16x16x32_bf16(aq0, ka0, s4a, 0, 0, 0);
      s4a = __builtin_amdgcn_mfma_f32_16x16x32_bf16(aq1, ka1, s4a, 0, 0, 0);
      __builtin_amdgcn_s_setprio(0);
      bool haveB = (st2 + 1 <= qt);
      v4f s4b = {};
      if (haveB) {
        int srB = srA + 16;
        v8bf kb0 = ldfrag(&Ks[srB * 64 + ((quad * 8) ^ swz)]);
        v8bf kb1 = ldfrag(&Ks[srB * 64 + ((32 + quad * 8) ^ swz)]);
        __builtin_amdgcn_s_setprio(1);
        s4b = __builtin_amdgcn_mfma_f32_16x16x32_bf16(aq0, kb0, s4b, 0, 0, 0);
        s4b = __builtin_amdgcn_mfma_f32_16x16x32_bf16(aq1, kb1, s4b, 0, 0, 0);
        __builtin_amdgcn_s_setprio(0);
      }
      float sca[4], scb[4];
#pragma unroll
      for (int rr = 0; rr < 4; ++rr) {
        int rowt = tb + quad * 4 + rr;
        sca[rr] = s4a[rr] * 0.125f;
        if (st2 == qt && st2 * 16 + m > rowt) sca[rr] = -1.0e9f;
        scb[rr] = haveB ? s4b[rr] * 0.125f : -1.0e30f;
        if (haveB && st2 + 1 == qt && (st2 + 1) * 16 + m > rowt) scb[rr] = -1.0e9f;
      }
      float pva[4], pvb[4], alpha[4];
#pragma unroll
      for (int rr = 0; rr < 4; ++rr) {
        float v = fmaxf(sca[rr], scb[rr]);
        v = fmaxf(v, __shfl_xor(v, 1));
        v = fmaxf(v, __shfl_xor(v, 2));
        v = fmaxf(v, __shfl_xor(v, 4));
        v = fmaxf(v, __shfl_xor(v, 8));
        float mn = fmaxf(mr[rr], v);
        alpha[rr] = __expf(mr[rr] - mn);
        pva[rr] = __expf(sca[rr] - mn);
        pvb[rr] = __expf(scb[rr] - mn);
        mr[rr] = mn;
      }
#pragma unroll
      for (int rr = 0; rr < 4; ++rr) {
        float s = pva[rr] + pvb[rr];
        s += __shfl_xor(s, 1); s += __shfl_xor(s, 2);
        s += __shfl_xor(s, 4); s += __shfl_xor(s, 8);
        lr_[rr] = lr_[rr] * alpha[rr] + s;
#pragma unroll
        for (int c = 0; c < 4; ++c) acc[c][rr] *= alpha[rr];
        Ps[w][(quad * 4 + rr) * 40 + m]      = f2bf(pva[rr]);
        Ps[w][(quad * 4 + rr) * 40 + 16 + m] = f2bf(pvb[rr]);
      }
      __asm__ volatile("" ::: "memory");  // keep P stores before frag reads
      v8bf pf = ldfrag(&Ps[w][m * 40 + quad * 8]);
      __builtin_amdgcn_s_setprio(1);
#pragma unroll
      for (int c = 0; c < 4; ++c) {
        int drow = c * 16 + m;
        v8bf vf = ldfrag(&Vt[drow * 512 +
                             ((st2 * 16 + quad * 8) ^ ((drow & 7) * 8))]);
        acc[c] = __builtin_amdgcn_mfma_f32_16x16x32_bf16(pf, vf, acc[c], 0, 0, 0);
      }
      __builtin_amdgcn_s_setprio(0);
    }
#pragma unroll
    for (int rr = 0; rr < 4; ++rr) {
      int t = tb + quad * 4 + rr;
      float inv = 1.f / lr_[rr];
      u16* op = og + obase + (size_t)t * 512;
#pragma unroll
      for (int c = 0; c < 4; ++c) op[c * 16 + m] = f2bf(acc[c][rr] * inv);
    }
  }
}

// ---------------------------------------------------------------------------
// Batched GEMV: wkey/wval/abase/ws per batch. grid (25, 32).
// ---------------------------------------------------------------------------
__global__ __launch_bounds__(256) void gemv_k(
    const float* __restrict__ qw_g, const float* __restrict__ Wwk,
    const float* __restrict__ bwk, const float* __restrict__ Wwv,
    const float* __restrict__ bwv, const float* __restrict__ Wg1,
    const float* __restrict__ bg1, const float* __restrict__ Wws,
    const float* __restrict__ bws, float* __restrict__ wkey_g,
    float* __restrict__ wval_g, float* __restrict__ abase_g,
    float* __restrict__ ws_g) {
  __shared__ float qs[512];
  __shared__ float prt[4][64];
  __shared__ float sred[8];
  int tid = threadIdx.x;
  int b = blockIdx.y, cg = blockIdx.x;
  qs[tid]       = qw_g[(size_t)b * 512 + tid];
  qs[tid + 256] = qw_g[(size_t)b * 512 + tid + 256];
  __syncthreads();
  if (cg == 24) {
    float p = qs[tid] * Wws[tid] + qs[tid + 256] * Wws[tid + 256];
    float tot = block_sum256(p, sred);
    if (tid == 0) {
      float wsv = 1.f / (1.f + __expf(-(tot + bws[0])));
      ws_g[b] = fminf(fmaxf(wsv, 0.f), 1.f);
    }
    return;
  }
  int sel = cg >> 3;
  int c0 = (cg & 7) * 64;
  const float* W = sel == 0 ? Wwk : (sel == 1 ? Wwv : Wg1);
  const float* bias = sel == 0 ? bwk : (sel == 1 ? bwv : bg1);
  float* dst = sel == 0 ? wkey_g : (sel == 1 ? wval_g : abase_g);
  int kg = tid >> 6, cl = tid & 63;
  const float* Wp = W + (size_t)(kg * 128) * 512 + c0 + cl;
  float acc = 0.f;
#pragma unroll 8
  for (int i = 0; i < 128; ++i) acc += qs[kg * 128 + i] * Wp[(size_t)i * 512];
  prt[kg][cl] = acc;
  __syncthreads();
  if (tid < 64)
    dst[(size_t)b * 512 + c0 + tid] =
        prt[0][tid] + prt[1][tid] + prt[2][tid] + prt[3][tid] + bias[c0 + tid];
}

// ---------------------------------------------------------------------------
// Episodic memory rest + gate, one block (256 thr) per batch element.
// ---------------------------------------------------------------------------
__global__ __launch_bounds__(256) void epi2_k(
    const float* __restrict__ qw_g, const float* __restrict__ wkey_g,
    const float* __restrict__ wval_g, const float* __restrict__ abase_g,
    const float* __restrict__ ws_g, const float* __restrict__ keys,
    const float* __restrict__ vals, const float* __restrict__ age,
    const float* __restrict__ strength, const float* __restrict__ Wg1,
    const float* __restrict__ Wg2, const float* __restrict__ bg2,
    const float* __restrict__ rms_read, float* __restrict__ read_f,
    float* __restrict__ gate_f, float* __restrict__ keys_out,
    float* __restrict__ vals_out, float* __restrict__ age_out,
    float* __restrict__ sn_out, float* __restrict__ gate_out) {
  int b = blockIdx.x;
  int tid = threadIdx.x;
  int w = tid >> 6, lane = tid & 63;
  __shared__ float qs[512], wkl[512], wvl[512];
  __shared__ float knorm[64], sr[64], swv[64], wread[64];
  __shared__ float sred[8];
  __shared__ float scal[2];
  __shared__ int bestk;
  __shared__ float novs;

  qs[tid]        = qw_g[(size_t)b * 512 + tid];
  qs[tid + 256]  = qw_g[(size_t)b * 512 + tid + 256];
  wkl[tid]       = wkey_g[(size_t)b * 512 + tid];
  wkl[tid + 256] = wkey_g[(size_t)b * 512 + tid + 256];
  wvl[tid]       = wval_g[(size_t)b * 512 + tid];
  wvl[tid + 256] = wval_g[(size_t)b * 512 + tid + 256];
  __syncthreads();
  float ws_s = ws_g[b];
  float p = qs[tid] * qs[tid] + qs[tid + 256] * qs[tid + 256];
  float tot = block_sum256(p, sred);
  if (tid == 0) scal[0] = 1.f / (sqrtf(tot) + 1e-6f);
  p = wkl[tid] * wkl[tid] + wkl[tid + 256] * wkl[tid + 256];
  tot = block_sum256(p, sred);
  if (tid == 0) scal[1] = 1.f / (sqrtf(tot) + 1e-6f);
  __syncthreads();
  float qscale = scal[0], wscale = scal[1];
  for (int k = w; k < 64; k += 4) {
    float kf[8];
    ld8f(keys + ((size_t)b * 64 + k) * 512 + lane * 8, kf);
    float s2 = 0.f, sq = 0.f, sw = 0.f;
#pragma unroll
    for (int i = 0; i < 8; ++i) {
      s2 += kf[i] * kf[i];
      sq += kf[i] * qs[lane * 8 + i];
      sw += kf[i] * wkl[lane * 8 + i];
    }
    s2 = wave_sum64(s2);
    sq = wave_sum64(sq);
    sw = wave_sum64(sw);
    if (lane == 0) {
      float kn = sqrtf(s2) + 1e-6f;
      knorm[k] = kn;
      float st = strength[b * 64 + k];
      float ag = age[b * 64 + k];
      sr[k] = (sq * qscale) / kn + 0.5f * logf(fminf(fmaxf(st, 0.001f), 1e9f)) -
              0.02f * ag + ((st > 0.001f) ? 0.f : -1000.f);
      swv[k] = (sw * wscale) / kn;
    }
  }
  __syncthreads();
  if (w == 0) {
    float v = sr[lane];
    float mx = v;
    mx = fmaxf(mx, __shfl_xor(mx, 1));  mx = fmaxf(mx, __shfl_xor(mx, 2));
    mx = fmaxf(mx, __shfl_xor(mx, 4));  mx = fmaxf(mx, __shfl_xor(mx, 8));
    mx = fmaxf(mx, __shfl_xor(mx, 16)); mx = fmaxf(mx, __shfl_xor(mx, 32));
    float e = __expf(v - mx);
    float sm = wave_sum64(e);
    wread[lane] = e / sm;
  } else if (w == 1) {
    float v = swv[lane];
    int idx = lane;
#pragma unroll
    for (int mm = 1; mm < 64; mm <<= 1) {
      float ov = __shfl_xor(v, mm);
      int oi = __shfl_xor(idx, mm);
      if (ov > v || (ov == v && oi < idx)) { v = ov; idx = oi; }
    }
    if (lane == 0) { bestk = idx; novs = 1.f - v; }
  }
  __syncthreads();
  float rv0 = 0.f, rv1 = 0.f;
  for (int k = 0; k < 64; ++k) {
    float wr = wread[k];
    const float* vp = vals + ((size_t)b * 64 + k) * 512;
    rv0 += wr * vp[tid];
    rv1 += wr * vp[tid + 256];
  }
  p = rv0 * rv0 + rv1 * rv1;
  tot = block_sum256(p, sred);
  float rinv = rsqrtf(tot * (1.f / 512.f) + 1e-6f);
  read_f[(size_t)b * 512 + tid]       = rv0 * rinv * rms_read[tid];
  read_f[(size_t)b * 512 + tid + 256] = rv1 * rinv * rms_read[tid + 256];
  if (tid < 64) {
    int k = tid;
    float hard = (k == bestk) ? 1.f : 0.f;
    float ag = age[b * 64 + k];
    age_out[b * 64 + k] = (ag + 1.f) * (1.f - hard);
    float st = strength[b * 64 + k];
    float s0 = st * 0.995f;
    float snv = s0 + hard * ws_s * (1.f - s0);
    sn_out[b * 64 + k] = fminf(fmaxf(snv, 0.001f), 1.f);
  }
  for (int k = w; k < 64; k += 4) {
    float re = (k == bestk) ? ws_s * 0.5f : 0.f;
    float kf[8], vf[8];
    ld8f(keys + ((size_t)b * 64 + k) * 512 + lane * 8, kf);
    ld8f(vals + ((size_t)b * 64 + k) * 512 + lane * 8, vf);
    float u[8], ss = 0.f;
#pragma unroll
    for (int i = 0; i < 8; ++i) {
      u[i] = (1.f - re) * kf[i] + re * wkl[lane * 8 + i];
      ss += u[i] * u[i];
    }
    ss = wave_sum64(ss);
    float uinv = 1.f / (sqrtf(ss) + 1e-6f);
    float ko[8], vo[8];
#pragma unroll
    for (int i = 0; i < 8; ++i) {
      ko[i] = u[i] * uinv;
      vo[i] = (1.f - re) * vf[i] + re * wvl[lane * 8 + i];
    }
    st8f(keys_out + ((size_t)b * 64 + k) * 512 + lane * 8, ko);
    st8f(vals_out + ((size_t)b * 64 + k) * 512 + lane * 8, vo);
  }
  __syncthreads();
  float nov = novs;
  float a0 = abase_g[(size_t)b * 512 + tid] +
             ws_s * Wg1[(size_t)512 * 512 + tid] +
             nov * Wg1[(size_t)513 * 512 + tid];
  float a1 = abase_g[(size_t)b * 512 + tid + 256] +
             ws_s * Wg1[(size_t)512 * 512 + tid + 256] +
             nov * Wg1[(size_t)513 * 512 + tid + 256];
  float h0 = a0 / (1.f + __expf(-a0));
  float h1v = a1 / (1.f + __expf(-a1));
  float gp = h0 * Wg2[tid] + h1v * Wg2[tid + 256];
  tot = block_sum256(gp, sred);
  if (tid == 0) {
    float g = 1.f / (1.f + __expf(-(tot + bg2[0])));
    gate_f[b] = g;
    gate_out[b] = g;
  }
}

// ---------------------------------------------------------------------------
// out = h2 + gate[b] * read[b, d]   (f32 in, f32 out)
// ---------------------------------------------------------------------------
__global__ __launch_bounds__(256) void final_k(const float* __restrict__ h2,
                                               const float* __restrict__ read_f,
                                               const float* __restrict__ gate_f,
                                               float* __restrict__ outp) {
  size_t i2 = ((size_t)blockIdx.x * 256 + threadIdx.x) * 2;
  int b = (int)(i2 >> 18);
  int d = (int)(i2 & 511);
  float g = gate_f[b];
  float2 h = *(const float2*)(h2 + i2);
  outp[i2]     = h.x + g * read_f[b * 512 + d];
  outp[i2 + 1] = h.y + g * read_f[b * 512 + d + 1];
}

// ---------------------------------------------------------------------------
extern "C" void kernel_launch(void* const* d_in, const int* in_sizes, int n_in,
                              void* d_out, int out_size, void* d_ws,
                              size_t ws_size, hipStream_t stream) {
  const float* x        = (const float*)d_in[0];
  const float* epi_keys = (const float*)d_in[1];
  const float* epi_vals = (const float*)d_in[2];
  const float* epi_age  = (const float*)d_in[3];
  const float* epi_str  = (const float*)d_in[4];
  const int*   pos      = (const int*)d_in[5];
  const float* rms1     = (const float*)d_in[6];
  const float* rms_kv   = (const float*)d_in[7];
  const float* rms2     = (const float*)d_in[8];
  const float* rms_read = (const float*)d_in[9];
  const float* Wq = (const float*)d_in[10]; const float* bq = (const float*)d_in[11];
  const float* Wk = (const float*)d_in[12]; const float* bk = (const float*)d_in[13];
  const float* Wv = (const float*)d_in[14]; const float* bv = (const float*)d_in[15];
  const float* Wo = (const float*)d_in[16]; const float* bo = (const float*)d_in[17];
  const float* W1 = (const float*)d_in[18]; const float* W2 = (const float*)d_in[19];
  const float* Wwk = (const float*)d_in[20]; const float* bwk = (const float*)d_in[21];
  const float* Wwv = (const float*)d_in[22]; const float* bwv = (const float*)d_in[23];
  const float* Wws = (const float*)d_in[24]; const float* bws = (const float*)d_in[25];
  const float* Wg1 = (const float*)d_in[26]; const float* bg1 = (const float*)d_in[27];
  const float* Wg2 = (const float*)d_in[28]; const float* bg2 = (const float*)d_in[29];

  float* out      = (float*)d_out;
  float* out_main = out;
  float* out_keys = out + 8388608;
  float* out_vals = out + 9437184;
  float* out_age  = out + 10485760;
  float* out_sn   = out + 10487808;
  float* out_gate = out + 10489856;

  char* w8 = (char*)d_ws;
  size_t off = 0;
  auto alloc = [&](size_t bytes) {
    char* pp = w8 + off;
    off += (bytes + 255) & ~(size_t)255;
    return pp;
  };
  u16* WTqkv = (u16*)alloc((size_t)1536 * 512 * 2);  // [WTq ; WTk ; WTv]
  u16* WTo   = (u16*)alloc(512 * 512 * 2);
  u16* WT1   = (u16*)alloc((size_t)4096 * 512 * 2);
  u16* WT2   = (u16*)alloc((size_t)512 * 2048 * 2);
  const size_t TB = (size_t)16384 * 512 * 2;  // 16 MB bf16 tensor
  u16* nrm  = (u16*)alloc(TB);           // | gact (64 MB) overlays nrm+qkvb
  u16* qkvb = (u16*)alloc(3 * TB);       // | [16384][1536]
  u16* ob   = (u16*)alloc(TB);           // | h2f (32 MB f32) overlays ob+n2
  u16* n2   = (u16*)alloc(TB);           // |
  float* h1f = (float*)alloc((size_t)16384 * 512 * 4);
  u16*   gact = nrm;
  float* h2f  = (float*)ob;
  float* bias_qkv = (float*)alloc(1536 * 4);
  float* tbl      = (float*)alloc((size_t)512 * 64 * 4);  // rope table
  float* qw_g     = (float*)alloc((size_t)32 * 512 * 4);
  float* wkey_g   = (float*)alloc((size_t)32 * 512 * 4);
  float* wval_g   = (float*)alloc((size_t)32 * 512 * 4);
  float* abase_g  = (float*)alloc((size_t)32 * 512 * 4);
  float* ws_g     = (float*)alloc(64 * 4);
  float* read_f   = (float*)alloc((size_t)32 * 512 * 4);
  float* gate_f   = (float*)alloc(64 * 4);

  // prep: transposes + bias concat + rope table + qw_g zero + rms(x->nrm)
  prep_k<<<8326, 256, 0, stream>>>(Wq, Wk, Wv, Wo, W1, W2, rms1, rms_kv, rms2,
                                   WTqkv, WTo, WT1, WT2, bq, bk, bv, bias_qkv,
                                   pos, tbl, qw_g, x, nrm);
  // fused Q|K|V projection (N=1536)
  gemm128_k<<<dim3(128, 12), 256, 0, stream>>>(nrm, WTqkv, bias_qkv, nullptr,
                                               qkvb, nullptr, nullptr, 1536, 512);
  // attention (rope fused via table)
  attn_k<<<256, 1024, 0, stream>>>(qkvb, tbl, ob);
  // output projection + residual (f32 out)
  gemm128_k<<<dim3(128, 4), 256, 0, stream>>>(ob, WTo, bo, x,
                                              nullptr, h1f, nullptr, 512, 512);
  // MLP
  rms_k<<<4096, 256, 0, stream>>>(h1f, n2);
  mlp1_k<<<dim3(128, 32), 256, 0, stream>>>(n2, WT1, gact);
  // MLP2 + residual; column-sum fused into epilogue -> qw_g
  gemm128_k<<<dim3(128, 4), 256, 0, stream>>>(gact, WT2, nullptr, h1f,
                                              nullptr, h2f, qw_g, 512, 2048);
  // episodic memory + gate
  gemv_k<<<dim3(25, 32), 256, 0, stream>>>(qw_g, Wwk, bwk, Wwv, bwv, Wg1, bg1,
                                           Wws, bws, wkey_g, wval_g, abase_g, ws_g);
  epi2_k<<<32, 256, 0, stream>>>(qw_g, wkey_g, wval_g, abase_g, ws_g, epi_keys,
                                 epi_vals, epi_age, epi_str, Wg1, Wg2, bg2,
                                 rms_read, read_f, gate_f, out_keys, out_vals,
                                 out_age, out_sn, out_gate);
  // final broadcast add
  final_k<<<16384, 256, 0, stream>>>(h2f, read_f, gate_f, out_main);
}